// Round 11
// baseline (214.376 us; speedup 1.0000x reference)
//
#include <hip/hip_runtime.h>
#include <math.h>

#define NF 10
#define TLEN 480
#define NWIN 24
#define WLEN 20
#define HID 64
#define NPAIR 45
#define DIN 210
#define NG 14
#define GATES 192
#define NGRP 256            // 4096 / 16 rows per group
#define FROW 212            // fp32 feat row length (53 float4)

typedef __attribute__((ext_vector_type(8))) short bf16x8;
typedef __attribute__((ext_vector_type(4))) float f32x4;

#define MFMA(a,b,c) __builtin_amdgcn_mfma_f32_16x16x32_bf16((a),(b),(c),0,0,0)

__device__ __forceinline__ int grp_of(int k){ return (k < 90) ? (k / 45) : 2 + (k - 90) / 10; }

__device__ __forceinline__ void split2(float x, short& hi, short& lo){
    unsigned u = __float_as_uint(x);
    hi = (short)(u >> 16);
    float hf = __uint_as_float(u & 0xffff0000u);
    lo = (short)(__float_as_uint(x - hf) >> 16);
}
__device__ __forceinline__ short bf16rne(float x){
    unsigned u = __float_as_uint(x);
    u += 0x7fffu + ((u >> 16) & 1u);
    return (short)(u >> 16);
}
__device__ __forceinline__ float sigm(float x){
    return __builtin_amdgcn_rcpf(1.f + __builtin_amdgcn_exp2f(x * -1.4426950408889634f));
}
__device__ __forceinline__ float tanhfast(float x){
    return 1.f - 2.f * __builtin_amdgcn_rcpf(1.f + __builtin_amdgcn_exp2f(x * 2.8853900817779268f));
}

// ---------------------------------------------------------------------------
// stats v7: rank-median replaced with odd-even transposition SORT NETWORK.
// Rationale (R10): rank block held ~45 live values (20 f32 + 20 i32 + temps)
// at VGPR=36 -> allocator pathology (remat/shuffle) = the invariant ~150us.
// The network is 190 CEs = 380 v_min/v_max, permutes the 20 floats in place,
// zero extra live registers, no vcc chains. Median by value is exactly the
// reference's order statistics. min comes free from s[0]; ratio pre-sort.
// ---------------------------------------------------------------------------
__global__ __launch_bounds__(256, 2)
void stats_kernel(const float* __restrict__ data, float* __restrict__ feat32,
                  float* __restrict__ accum)
{
    __shared__ __align__(16) float tile[NWIN][FROW];    // 20.35 KB
    __shared__ float mean_s[240], std_s[240];           // 1.9 KB
    __shared__ float sgs[NG], sgq[NG];
    int b = blockIdx.x, tid = threadIdx.x;
    const float* src = data + (size_t)b * (NF * TLEN);

    if (tid < NG){ sgs[tid] = 0.f; sgq[tid] = 0.f; }
    if (tid >= 200 && tid < 248) tile[(tid - 200) / 2][210 + (tid & 1)] = 0.f; // zero pad cols

    if (tid < 240){
        int f = tid / NWIN, nw = tid % NWIN;
        float v[WLEN];
        {
            const float4* p4 = (const float4*)&src[f * TLEN + nw * WLEN];
            #pragma unroll
            for (int i = 0; i < 5; ++i){
                float4 u = p4[i];
                v[i * 4 + 0] = u.x; v[i * 4 + 1] = u.y;
                v[i * 4 + 2] = u.z; v[i * 4 + 3] = u.w;
            }
        }
        float sum = 0.f, wsum = 0.f;
        #pragma unroll
        for (int i = 0; i < WLEN; ++i){
            sum += v[i];
            wsum += v[i] * ((float)(i + 1) * (1.0f / 210.0f));
        }
        float mean = sum * (1.0f / WLEN);
        float var = 0.f, m3 = 0.f, m4 = 0.f;
        #pragma unroll
        for (int i = 0; i < WLEN; ++i){
            float c = v[i] - mean, c2 = c * c;
            var += c2; m3 += c2 * c; m4 += c2 * c2;
        }
        var *= 0.05f; m3 *= 0.05f; m4 *= 0.05f;
        float sd = sqrtf(var);
        float ratio = v[WLEN - 1] / (v[0] + 0.01f) - 1.0f;   // original order!

        // odd-even transposition sort: 20 rounds, 190 CEs, min/max only
        #pragma unroll
        for (int r = 0; r < WLEN; ++r){
            #pragma unroll
            for (int i = (r & 1); i + 1 < WLEN; i += 2){
                float lo = fminf(v[i], v[i + 1]);
                float hi = fmaxf(v[i], v[i + 1]);
                v[i] = lo; v[i + 1] = hi;
            }
        }
        float minv = v[0];
        float median = 0.5f * (v[9] + v[10]);

        float s3 = sd * sd * sd;
        tile[nw][ 90 + f] = sd;
        tile[nw][100 + f] = mean / (sd + 0.01f);
        tile[nw][110 + f] = ratio;
        tile[nw][120 + f] = wsum;
        tile[nw][130 + f] = mean;
        tile[nw][140 + f] = minv;
        tile[nw][150 + f] = var;
        tile[nw][160 + f] = sum;
        tile[nw][170 + f] = median;
        tile[nw][180 + f] = m3 / (s3 + 0.01f);
        tile[nw][190 + f] = m4 / (s3 * sd + 0.01f) - 3.0f;
        tile[nw][200 + f] = sum;
        mean_s[f * NWIN + nw] = mean;
        std_s[f * NWIN + nw] = sd;
    }
    __syncthreads();   // singles staged (mean_s/std_s ready)

    // pairs: Gram via MFMA. wave w handles nw = w*6 .. w*6+5.
    {
        int w = tid >> 6, l = tid & 63;
        int f = l & 15, kb = l >> 4;
        #pragma unroll 1
        for (int s = 0; s < 6; ++s){
            int nw = w * 6 + s;
            float vv[8];
            #pragma unroll
            for (int j = 0; j < 8; ++j) vv[j] = 0.f;
            if (f < NF && kb < 3){
                const float* p = &src[f * TLEN + nw * WLEN + kb * 8];
                float4 u0 = *(const float4*)p;
                vv[0] = u0.x; vv[1] = u0.y; vv[2] = u0.z; vv[3] = u0.w;
                if (kb < 2){
                    float4 u1 = *(const float4*)(p + 4);
                    vv[4] = u1.x; vv[5] = u1.y; vv[6] = u1.z; vv[7] = u1.w;
                }
            }
            bf16x8 Fh, Fl;
            #pragma unroll
            for (int j = 0; j < 8; ++j){ short hi, lo; split2(vv[j], hi, lo); Fh[j] = hi; Fl[j] = lo; }
            f32x4 g = {0.f, 0.f, 0.f, 0.f};
            g = MFMA(Fh, Fh, g);
            g = MFMA(Fh, Fl, g);
            g = MFMA(Fl, Fh, g);
            // C-layout: col fb = l&15, row fa = kb*4 + i
            #pragma unroll
            for (int i = 0; i < 4; ++i){
                int fa = kb * 4 + i, fb = f;
                if (fa < fb && fb < NF){
                    float ma = mean_s[fa * NWIN + nw], mb = mean_s[fb * NWIN + nw];
                    float sa = std_s[fa * NWIN + nw], sb = std_s[fb * NWIN + nw];
                    float cov = (g[i] - (float)WLEN * ma * mb) * (1.0f / (WLEN - 1));
                    int pi = (((19 - fa) * fa) >> 1) + fb - fa - 1;
                    tile[nw][pi] = cov / (sa * sb + 0.01f);
                    tile[nw][NPAIR + pi] = cov;
                }
            }
        }
    }
    __syncthreads();   // tile complete

    // fused BN partial sums (reads tile)
    for (int task = tid; task < NWIN * NG; task += 256){
        int g = task % NG, t = task / NG;
        int ch0 = (g == 0) ? 0 : (g == 1) ? 45 : 90 + 10 * (g - 2);
        int n = (g < 2) ? 45 : 10;
        float s = 0.f, q = 0.f;
        for (int i = 0; i < n; ++i){ float vv = tile[t][ch0 + i]; s += vv; q += vv * vv; }
        atomicAdd(&sgs[g], s);
        atomicAdd(&sgq[g], q);
    }
    // coalesced row writes: [grp][t][e][FROW]
    {
        int grp = b >> 4, e = b & 15;
        for (int q = tid; q < NWIN * 53; q += 256){
            int t = q / 53, c = (q % 53) * 4;
            size_t rbase = (((size_t)grp * NWIN + t) * 16 + e) * FROW + c;
            *(float4*)&feat32[rbase] = *(const float4*)&tile[t][c];
        }
    }
    __syncthreads();
    if (tid < NG){
        atomicAdd(&accum[tid], sgs[tid]);
        atomicAdd(&accum[NG + tid], sgq[tid]);
    }
}

// ---------------------------------------------------------------------------
// prep: BN scale fold into Wih0 (bf16 RNE) + hidden weights bf16, MFMA
// B-fragment layout; bf0 = bih0 + Wih0 @ shift.
// ---------------------------------------------------------------------------
__global__ __launch_bounds__(256)
void prep_kernel(const float* __restrict__ Wih0, const float* __restrict__ Whh0,
                 const float* __restrict__ Wih1, const float* __restrict__ Whh1,
                 const float* __restrict__ bih0, const float* __restrict__ accum,
                 const float* __restrict__ conv_w, const float* __restrict__ bn_gamma,
                 const float* __restrict__ bn_beta,
                 short* __restrict__ WHh, short* __restrict__ W0h, float* __restrict__ bf0)
{
    __shared__ float scs[NG], shs[NG];
    int tid = threadIdx.x;
    if (tid < NG){
        float N = (tid < 2) ? 4096.f * NPAIR * NWIN : 4096.f * NF * NWIN;
        float m = accum[tid] / N;
        float v = accum[NG + tid] / N - m * m;
        float cw = conv_w[0];
        float A = bn_gamma[tid] * rsqrtf(cw * cw * v + 1e-5f);
        scs[tid] = A * cw;
        shs[tid] = bn_beta[tid] - A * cw * m;
    }
    __syncthreads();
    const int NH = 3 * 2 * 12 * 64 * 8;    // 36864
    const int N0 = 7 * 12 * 64 * 8;        // 43008
    for (int i = blockIdx.x * 256 + tid; i < NH + N0; i += gridDim.x * 256){
        if (i < NH){
            int j = i & 7, lane = (i >> 3) & 63, rest = i >> 9;
            int ct = rest % 12; rest /= 12;
            int ks = rest & 1, m = rest >> 1;
            int gg = ct * 16 + (lane & 15);
            int k = ks * 32 + ((lane >> 4) << 3) + j;
            const float* Wm = (m == 0) ? Whh0 : (m == 1) ? Wih1 : Whh1;
            WHh[i] = bf16rne(Wm[gg * HID + k]);
        } else {
            int e2 = i - NH;
            int j = e2 & 7, lane = (e2 >> 3) & 63, rest = e2 >> 9;
            int ct = rest % 12, ks = rest / 12;
            int gg = ct * 16 + (lane & 15);
            int k = ks * 32 + ((lane >> 4) << 3) + j;
            float v = (k < DIN) ? Wih0[gg * DIN + k] * scs[grp_of(k)] : 0.f;
            W0h[e2] = bf16rne(v);
        }
    }
    if (blockIdx.x == 0 && tid < GATES){
        float s = bih0[tid];
        for (int k = 0; k < DIN; ++k) s += Wih0[tid * DIN + k] * shs[grp_of(k)];
        bf0[tid] = s;
    }
}

// ---------------------------------------------------------------------------
// rec: 256 blocks x 512 thr. Waves 0-3 = MFMA only (weights VGPR-resident,
// 2-pass A(hi+lo) x B(hi)). Waves 4-7 = helpers: stage+split feat rows into
// fragment LDS + all pointwise (fast exp2), h state in helper registers.
// ---------------------------------------------------------------------------
__device__ __forceinline__ void stage_fa(short (*fab)[64][8], int tix,
                                         const float* __restrict__ feat32, int ht)
{
    for (int q = ht; q < 448; q += 256){
        int c = q >> 4, e = q & 15;
        float vv[8];
        const float* src = &feat32[((size_t)tix * 16 + e) * FROW + c * 8];
        if (c < 26){
            float4 u0 = *(const float4*)src, u1 = *(const float4*)(src + 4);
            vv[0]=u0.x; vv[1]=u0.y; vv[2]=u0.z; vv[3]=u0.w;
            vv[4]=u1.x; vv[5]=u1.y; vv[6]=u1.z; vv[7]=u1.w;
        } else if (c == 26){
            float4 u0 = *(const float4*)src;
            vv[0]=u0.x; vv[1]=u0.y; vv[2]=u0.z; vv[3]=u0.w;
            vv[4]=0.f; vv[5]=0.f; vv[6]=0.f; vv[7]=0.f;
        } else {
            #pragma unroll
            for (int j = 0; j < 8; ++j) vv[j] = 0.f;
        }
        bf16x8 h8, l8;
        #pragma unroll
        for (int j = 0; j < 8; ++j){ short hi, lo; split2(vv[j], hi, lo); h8[j] = hi; l8[j] = lo; }
        *(bf16x8*)&fab[(c >> 2) * 2 + 0][e + 16 * (c & 3)][0] = h8;
        *(bf16x8*)&fab[(c >> 2) * 2 + 1][e + 16 * (c & 3)][0] = l8;
    }
}

__global__ __launch_bounds__(512, 2)
void rec_kernel(const float* __restrict__ feat32,
                const short* __restrict__ WHh, const short* __restrict__ W0h,
                const float* __restrict__ bf0, const float* __restrict__ bhh0,
                const float* __restrict__ bih1, const float* __restrict__ bhh1,
                float* __restrict__ out)
{
    __shared__ __align__(16) short fa[2][14][64][8];   // 28.7 KB
    __shared__ __align__(16) short hp[4][16][72];      // 9.2 KB
    __shared__ float aar[4][16][68];                   // 17.4 KB
    int tid = threadIdx.x;
    int w = tid >> 6, l = tid & 63;
    int blk = blockIdx.x;

    for (int i = tid; i < 4 * 16 * 72; i += 512) ((short*)hp)[i] = 0;

    if (w < 4){
        int lm = l & 15, kb = l >> 4;
        int jc = w * 16 + lm;
        bf16x8 WH_[3][2][3];
        #pragma unroll
        for (int m = 0; m < 3; ++m)
            #pragma unroll
            for (int ks = 0; ks < 2; ++ks)
                #pragma unroll
                for (int ro = 0; ro < 3; ++ro)
                    WH_[m][ks][ro] = *(const bf16x8*)&WHh[((((m * 2 + ks) * 12) + (ro * 4 + w)) * 64 + l) * 8];
        bf16x8 W0_[7][3];
        #pragma unroll
        for (int ks = 0; ks < 7; ++ks)
            #pragma unroll
            for (int ro = 0; ro < 3; ++ro)
                W0_[ks][ro] = *(const bf16x8*)&W0h[(((ks * 12) + (ro * 4 + w)) * 64 + l) * 8];

        float cr0 = bf0[jc]       + bhh0[jc];
        float cz0 = bf0[jc + 64]  + bhh0[jc + 64];
        float cin0 = bf0[jc + 128];
        float chn0 = bhh0[jc + 128];
        float cr1 = bih1[jc]      + bhh1[jc];
        float cz1 = bih1[jc + 64] + bhh1[jc + 64];
        float cin1 = bih1[jc + 128];
        float chn1 = bhh1[jc + 128];

        __syncthreads();   // P0
        #pragma unroll 1
        for (int t = 0; t < NWIN; ++t){
            int buf = t & 1;
            bf16x8 h0h[2], h0l[2], h1h[2], h1l[2];
            #pragma unroll
            for (int ks = 0; ks < 2; ++ks){
                int off = ks * 32 + kb * 8;
                h0h[ks] = *(const bf16x8*)&hp[0][lm][off];
                h0l[ks] = *(const bf16x8*)&hp[1][lm][off];
                h1h[ks] = *(const bf16x8*)&hp[2][lm][off];
                h1l[ks] = *(const bf16x8*)&hp[3][lm][off];
            }
            f32x4 ar0 = {cr0, cr0, cr0, cr0};
            f32x4 az0 = {cz0, cz0, cz0, cz0};
            f32x4 ain0 = {cin0, cin0, cin0, cin0};
            f32x4 ahn0 = {chn0, chn0, chn0, chn0};
            f32x4 ar1 = {cr1, cr1, cr1, cr1};
            f32x4 az1 = {cz1, cz1, cz1, cz1};
            f32x4 ahn1 = {chn1, chn1, chn1, chn1};
            #pragma unroll
            for (int ks = 0; ks < 2; ++ks){
                ar0 = MFMA(h0h[ks], WH_[0][ks][0], ar0);  ar0 = MFMA(h0l[ks], WH_[0][ks][0], ar0);
                az0 = MFMA(h0h[ks], WH_[0][ks][1], az0);  az0 = MFMA(h0l[ks], WH_[0][ks][1], az0);
                ahn0 = MFMA(h0h[ks], WH_[0][ks][2], ahn0); ahn0 = MFMA(h0l[ks], WH_[0][ks][2], ahn0);
                ar1 = MFMA(h1h[ks], WH_[2][ks][0], ar1);  ar1 = MFMA(h1l[ks], WH_[2][ks][0], ar1);
                az1 = MFMA(h1h[ks], WH_[2][ks][1], az1);  az1 = MFMA(h1l[ks], WH_[2][ks][1], az1);
                ahn1 = MFMA(h1h[ks], WH_[2][ks][2], ahn1); ahn1 = MFMA(h1l[ks], WH_[2][ks][2], ahn1);
            }
            #pragma unroll
            for (int ks = 0; ks < 7; ++ks){
                bf16x8 Fh = *(const bf16x8*)&fa[buf][ks * 2 + 0][l][0];
                bf16x8 Fl = *(const bf16x8*)&fa[buf][ks * 2 + 1][l][0];
                ar0 = MFMA(Fh, W0_[ks][0], ar0);  ar0 = MFMA(Fl, W0_[ks][0], ar0);
                az0 = MFMA(Fh, W0_[ks][1], az0);  az0 = MFMA(Fl, W0_[ks][1], az0);
                ain0 = MFMA(Fh, W0_[ks][2], ain0); ain0 = MFMA(Fl, W0_[ks][2], ain0);
            }
            #pragma unroll
            for (int i = 0; i < 4; ++i){
                int row = kb * 4 + i;
                aar[0][row][jc] = ar0[i];
                aar[1][row][jc] = az0[i];
                aar[2][row][jc] = ain0[i];
                aar[3][row][jc] = ahn0[i];
            }
            __syncthreads();   // B1
            __syncthreads();   // B2 (pointwise l0 done)
            bf16x8 n0h[2], n0l[2];
            #pragma unroll
            for (int ks = 0; ks < 2; ++ks){
                int off = ks * 32 + kb * 8;
                n0h[ks] = *(const bf16x8*)&hp[0][lm][off];
                n0l[ks] = *(const bf16x8*)&hp[1][lm][off];
            }
            f32x4 ain1 = {cin1, cin1, cin1, cin1};
            #pragma unroll
            for (int ks = 0; ks < 2; ++ks){
                ar1 = MFMA(n0h[ks], WH_[1][ks][0], ar1);  ar1 = MFMA(n0l[ks], WH_[1][ks][0], ar1);
                az1 = MFMA(n0h[ks], WH_[1][ks][1], az1);  az1 = MFMA(n0l[ks], WH_[1][ks][1], az1);
                ain1 = MFMA(n0h[ks], WH_[1][ks][2], ain1); ain1 = MFMA(n0l[ks], WH_[1][ks][2], ain1);
            }
            #pragma unroll
            for (int i = 0; i < 4; ++i){
                int row = kb * 4 + i;
                aar[0][row][jc] = ar1[i];
                aar[1][row][jc] = az1[i];
                aar[2][row][jc] = ain1[i];
                aar[3][row][jc] = ahn1[i];
            }
            __syncthreads();   // B3
            __syncthreads();   // B4 (pointwise l1 done)
        }
    } else {
        int ht = tid - 256;
        int j = ht & 63, rr = ht >> 6;
        float h0r[4] = {0.f, 0.f, 0.f, 0.f};
        float h1r[4] = {0.f, 0.f, 0.f, 0.f};
        stage_fa(fa[0], blk * NWIN + 0, feat32, ht);
        __syncthreads();   // P0
        #pragma unroll 1
        for (int t = 0; t < NWIN; ++t){
            int buf = t & 1;
            if (t < NWIN - 1) stage_fa(fa[buf ^ 1], blk * NWIN + t + 1, feat32, ht);
            __syncthreads();   // B1
            #pragma unroll
            for (int i = 0; i < 4; ++i){
                int row = rr + i * 4;
                float a  = aar[0][row][j], z_ = aar[1][row][j];
                float in_ = aar[2][row][j], hn = aar[3][row][j];
                float rg = sigm(a), zg = sigm(z_);
                float nn = tanhfast(in_ + rg * hn);
                float h = (1.f - zg) * nn + zg * h0r[i];
                h0r[i] = h;
                short hi, lo; split2(h, hi, lo);
                hp[0][row][j] = hi;
                hp[1][row][j] = lo;
            }
            __syncthreads();   // B2
            __syncthreads();   // B3
            #pragma unroll
            for (int i = 0; i < 4; ++i){
                int row = rr + i * 4;
                float a  = aar[0][row][j], z_ = aar[1][row][j];
                float in_ = aar[2][row][j], hn = aar[3][row][j];
                float rg = sigm(a), zg = sigm(z_);
                float nn = tanhfast(in_ + rg * hn);
                float h = (1.f - zg) * nn + zg * h1r[i];
                h1r[i] = h;
                short hi, lo; split2(h, hi, lo);
                hp[2][row][j] = hi;
                hp[3][row][j] = lo;
            }
            __syncthreads();   // B4
        }
        #pragma unroll
        for (int i = 0; i < 4; ++i)
            out[((size_t)(blk * 16) + rr + i * 4) * HID + j] = h1r[i];
    }
}

// ---------------------------------------------------------------------------
extern "C" void kernel_launch(void* const* d_in, const int* in_sizes, int n_in,
                              void* d_out, int out_size, void* d_ws, size_t ws_size,
                              hipStream_t stream) {
    const float* data     = (const float*)d_in[0];
    const float* conv_w   = (const float*)d_in[1];
    const float* bn_gamma = (const float*)d_in[3];
    const float* bn_beta  = (const float*)d_in[4];
    const float* Wih0     = (const float*)d_in[5];
    const float* Whh0     = (const float*)d_in[6];
    const float* bih0     = (const float*)d_in[7];
    const float* bhh0     = (const float*)d_in[8];
    const float* Wih1     = (const float*)d_in[9];
    const float* Whh1     = (const float*)d_in[10];
    const float* bih1     = (const float*)d_in[11];
    const float* bhh1     = (const float*)d_in[12];
    float* out = (float*)d_out;

    char* ws = (char*)d_ws;
    const size_t feat32_bytes = (size_t)NGRP * NWIN * 16 * FROW * 4;   // 83,361,792
    const size_t WH_BYTES = 3 * 2 * 12 * 64 * 8 * 2;                    // 73,728
    const size_t W0_BYTES = 7 * 12 * 64 * 8 * 2;                        // 86,016

    float* feat32 = (float*)ws;
    short* WHh = (short*)(ws + feat32_bytes);
    short* W0h = (short*)(ws + feat32_bytes + WH_BYTES);
    float* bf0 = (float*)(ws + feat32_bytes + WH_BYTES + W0_BYTES);
    float* accum = (float*)(ws + feat32_bytes + WH_BYTES + W0_BYTES + 1024);

    hipMemsetAsync(accum, 0, 2 * NG * sizeof(float), stream);
    stats_kernel<<<4096, 256, 0, stream>>>(data, feat32, accum);
    prep_kernel<<<64, 256, 0, stream>>>(Wih0, Whh0, Wih1, Whh1, bih0, accum,
                                        conv_w, bn_gamma, bn_beta, WHh, W0h, bf0);
    rec_kernel<<<NGRP, 512, 0, stream>>>(feat32, WHh, W0h, bf0,
                                         bhh0, bih1, bhh1, out);
}

// Round 13
// 180.579 us; speedup vs baseline: 1.1872x; 1.1872x over previous
//
#include <hip/hip_runtime.h>
#include <math.h>

#define NF 10
#define TLEN 480
#define NWIN 24
#define WLEN 20
#define HID 64
#define NPAIR 45
#define DIN 210
#define NG 14
#define GATES 192
#define NGRP 256            // 4096 / 16 rows per group
#define FROW 212            // fp32 feat row length (53 float4)
#define NW1 15360           // S1 waves: 3840 blocks x 4
#define NW2 16384           // S2 waves: 4096 blocks x 4

typedef __attribute__((ext_vector_type(8))) short bf16x8;
typedef __attribute__((ext_vector_type(4))) float f32x4;

#define MFMA(a,b,c) __builtin_amdgcn_mfma_f32_16x16x32_bf16((a),(b),(c),0,0,0)

__device__ __forceinline__ int grp_of(int k){ return (k < 90) ? (k / 45) : 2 + (k - 90) / 10; }

__device__ __forceinline__ void split2(float x, short& hi, short& lo){
    unsigned u = __float_as_uint(x);
    hi = (short)(u >> 16);
    float hf = __uint_as_float(u & 0xffff0000u);
    lo = (short)(__float_as_uint(x - hf) >> 16);
}
__device__ __forceinline__ short bf16rne(float x){
    unsigned u = __float_as_uint(x);
    u += 0x7fffu + ((u >> 16) & 1u);
    return (short)(u >> 16);
}
__device__ __forceinline__ float sigm(float x){
    return __builtin_amdgcn_rcpf(1.f + __builtin_amdgcn_exp2f(x * -1.4426950408889634f));
}
__device__ __forceinline__ float tanhfast(float x){
    return 1.f - 2.f * __builtin_amdgcn_rcpf(1.f + __builtin_amdgcn_exp2f(x * 2.8853900817779268f));
}

// ---------------------------------------------------------------------------
// S1: singles, fully flattened. task=(b,f,t); NO LDS, NO barriers; BN group
// sums (groups 2..13) via wave shfl reduction -> per-wave partials.
// ---------------------------------------------------------------------------
__global__ __launch_bounds__(256)
void s1_kernel(const float* __restrict__ data, float* __restrict__ feat32,
               float* __restrict__ part1)
{
    int task = blockIdx.x * 256 + threadIdx.x;
    int b = task / 240, r = task % 240;
    int f = r / NWIN, t = r % NWIN;
    const float* p = data + (size_t)b * (NF * TLEN) + f * TLEN + t * WLEN;

    float v[WLEN];
    {
        float4 a0 = *(const float4*)(p + 0);
        float4 a1 = *(const float4*)(p + 4);
        float4 a2 = *(const float4*)(p + 8);
        float4 a3 = *(const float4*)(p + 12);
        float4 a4 = *(const float4*)(p + 16);
        v[0]=a0.x; v[1]=a0.y; v[2]=a0.z; v[3]=a0.w;
        v[4]=a1.x; v[5]=a1.y; v[6]=a1.z; v[7]=a1.w;
        v[8]=a2.x; v[9]=a2.y; v[10]=a2.z; v[11]=a2.w;
        v[12]=a3.x; v[13]=a3.y; v[14]=a3.z; v[15]=a3.w;
        v[16]=a4.x; v[17]=a4.y; v[18]=a4.z; v[19]=a4.w;
    }
    float sum = 0.f, wsum = 0.f;
    #pragma unroll
    for (int i = 0; i < WLEN; ++i){
        sum += v[i];
        wsum += v[i] * ((float)(i + 1) * (1.0f / 210.0f));
    }
    float mean = sum * (1.0f / WLEN);
    float var = 0.f, m3 = 0.f, m4 = 0.f;
    #pragma unroll
    for (int i = 0; i < WLEN; ++i){
        float c = v[i] - mean, c2 = c * c;
        var += c2; m3 += c2 * c; m4 += c2 * c2;
    }
    var *= 0.05f; m3 *= 0.05f; m4 *= 0.05f;
    float sd = sqrtf(var);
    float ratio = v[WLEN - 1] / (v[0] + 0.01f) - 1.0f;   // pre-sort order

    // odd-even transposition sort (190 CEs, min/max only)
    #pragma unroll
    for (int rr = 0; rr < WLEN; ++rr){
        #pragma unroll
        for (int i = (rr & 1); i + 1 < WLEN; i += 2){
            float lo = fminf(v[i], v[i + 1]);
            float hi = fmaxf(v[i], v[i + 1]);
            v[i] = lo; v[i + 1] = hi;
        }
    }
    float minv = v[0];
    float median = 0.5f * (v[9] + v[10]);
    float s3 = sd * sd * sd;
    float mos = mean / (sd + 0.01f);
    float skew = m3 / (s3 + 0.01f);
    float kurt = m4 / (s3 * sd + 0.01f) - 3.0f;

    size_t base = (((size_t)(b >> 4) * NWIN + t) * 16 + (b & 15)) * FROW;
    feat32[base +  90 + f] = sd;
    feat32[base + 100 + f] = mos;
    feat32[base + 110 + f] = ratio;
    feat32[base + 120 + f] = wsum;
    feat32[base + 130 + f] = mean;
    feat32[base + 140 + f] = minv;
    feat32[base + 150 + f] = var;
    feat32[base + 160 + f] = sum;
    feat32[base + 170 + f] = median;
    feat32[base + 180 + f] = skew;
    feat32[base + 190 + f] = kurt;
    feat32[base + 200 + f] = sum;

    // wave-level BN partials, groups 2..13 in channel order
    float val[12] = {sd, mos, ratio, wsum, mean, minv, var, sum, median, skew, kurt, sum};
    int wid = blockIdx.x * 4 + (threadIdx.x >> 6);
    int lane = threadIdx.x & 63;
    #pragma unroll
    for (int j = 0; j < 12; ++j){
        float a = val[j], q = val[j] * val[j];
        #pragma unroll
        for (int m = 1; m < 64; m <<= 1){
            a += __shfl_xor(a, m);
            q += __shfl_xor(q, m);
        }
        if (lane == 0){
            part1[(size_t)(2 * j) * NW1 + wid] = a;
            part1[(size_t)(2 * j + 1) * NW1 + wid] = q;
        }
    }
}

// ---------------------------------------------------------------------------
// S2: pairs via Gram MFMA with injected all-ones row 10:
//   G[10][f] = sum(X_f),  G[f][f] = sum(X_f^2)  -> mean/std in-register.
// NO LDS, NO barriers, no dependency on S1. Writes corr/cov + row pads.
// BN groups 0,1 partials per wave.
// ---------------------------------------------------------------------------
__global__ __launch_bounds__(256)
void s2_kernel(const float* __restrict__ data, float* __restrict__ feat32,
               float* __restrict__ part2)
{
    int tid = threadIdx.x, b = blockIdx.x;
    int w = tid >> 6, l = tid & 63;
    int f = l & 15, kb = l >> 4;
    const float* src = data + (size_t)b * (NF * TLEN);
    float cs = 0.f, cq = 0.f, vs = 0.f, vq = 0.f;

    #pragma unroll 1
    for (int s = 0; s < 6; ++s){
        int nw = w * 6 + s;
        float vv[8];
        #pragma unroll
        for (int j = 0; j < 8; ++j) vv[j] = 0.f;
        if (f < NF && kb < 3){
            const float* p = &src[f * TLEN + nw * WLEN + kb * 8];
            float4 u0 = *(const float4*)p;
            vv[0] = u0.x; vv[1] = u0.y; vv[2] = u0.z; vv[3] = u0.w;
            if (kb < 2){
                float4 u1 = *(const float4*)(p + 4);
                vv[4] = u1.x; vv[5] = u1.y; vv[6] = u1.z; vv[7] = u1.w;
            }
        } else if (f == NF){
            // ones-row 10: k<20 -> 1
            int kbase = kb * 8;
            for (int j = 0; j < 8; ++j) vv[j] = (kbase + j < WLEN) ? 1.f : 0.f;
        }
        bf16x8 Fh, Fl;
        #pragma unroll
        for (int j = 0; j < 8; ++j){ short hi, lo; split2(vv[j], hi, lo); Fh[j] = hi; Fl[j] = lo; }
        f32x4 g = {0.f, 0.f, 0.f, 0.f};
        g = MFMA(Fh, Fh, g);
        g = MFMA(Fh, Fl, g);
        g = MFMA(Fl, Fh, g);

        // stat extraction (all shuffles unconditional)
        float d_own = ((f >> 2) == kb) ? g[f & 3] : 0.f;   // G[f][f] holder
        float sumB = __shfl(g[2], 32 + f);                  // G[10][f] (row 10 = reg 2 of kb=2)
        float diagB = __shfl(d_own, f + 16 * (f >> 2));
        float meanB = sumB * 0.05f;
        float varB = fmaxf(diagB * 0.05f - meanB * meanB, 0.f);
        float stdB = sqrtf(varB);

        float sumA[4], diagA[4];
        #pragma unroll
        for (int i = 0; i < 4; ++i){
            int fa = kb * 4 + i;
            sumA[i] = __shfl(g[2], 32 + fa);
            diagA[i] = __shfl(d_own, fa + 16 * (fa >> 2));
        }
        size_t base = (((size_t)(b >> 4) * NWIN + nw) * 16 + (b & 15)) * FROW;
        #pragma unroll
        for (int i = 0; i < 4; ++i){
            int fa = kb * 4 + i, fb = f;
            if (fa < fb && fb < NF){
                float meanA = sumA[i] * 0.05f;
                float varA = fmaxf(diagA[i] * 0.05f - meanA * meanA, 0.f);
                float stdA = sqrtf(varA);
                float cov = (g[i] - (float)WLEN * meanA * meanB) * (1.0f / (WLEN - 1));
                float corr = cov / (stdA * stdB + 0.01f);
                int pi = (((19 - fa) * fa) >> 1) + fb - fa - 1;
                feat32[base + pi] = corr;
                feat32[base + NPAIR + pi] = cov;
                cs += corr; cq += corr * corr;
                vs += cov;  vq += cov * cov;
            }
        }
        if (l == 0){ feat32[base + 210] = 0.f; feat32[base + 211] = 0.f; }
    }

    // wave-level BN partials: g0=corr, g1=cov
    float acc[4] = {cs, cq, vs, vq};
    int wid = b * 4 + w;
    #pragma unroll
    for (int j = 0; j < 4; ++j){
        float a = acc[j];
        #pragma unroll
        for (int m = 1; m < 64; m <<= 1) a += __shfl_xor(a, m);
        if (l == 0) part2[(size_t)j * NW2 + wid] = a;   // j = g*2+which
    }
}

// ---------------------------------------------------------------------------
// reduceA: 28 blocks, one per accum entry. accum[which*14+g].
// ---------------------------------------------------------------------------
__global__ __launch_bounds__(256)
void reduce_kernel(const float* __restrict__ part1, const float* __restrict__ part2,
                   float* __restrict__ accum)
{
    __shared__ float red[256];
    int j = blockIdx.x;            // 0..27
    int g = j % NG, which = j / NG;
    const float* base; int n;
    if (g < 2){ base = part2 + (size_t)(g * 2 + which) * NW2; n = NW2; }
    else      { base = part1 + (size_t)((g - 2) * 2 + which) * NW1; n = NW1; }
    int tid = threadIdx.x;
    float s = 0.f;
    for (int i = tid; i < n; i += 256) s += base[i];
    red[tid] = s; __syncthreads();
    for (int step = 128; step > 0; step >>= 1){
        if (tid < step) red[tid] += red[tid + step];
        __syncthreads();
    }
    if (tid == 0) accum[which * NG + g] = red[0];
}

// ---------------------------------------------------------------------------
// prep: BN scale fold into Wih0 (bf16 RNE) + hidden weights bf16, MFMA
// B-fragment layout; bf0 = bih0 + Wih0 @ shift.  (unchanged)
// ---------------------------------------------------------------------------
__global__ __launch_bounds__(256)
void prep_kernel(const float* __restrict__ Wih0, const float* __restrict__ Whh0,
                 const float* __restrict__ Wih1, const float* __restrict__ Whh1,
                 const float* __restrict__ bih0, const float* __restrict__ accum,
                 const float* __restrict__ conv_w, const float* __restrict__ bn_gamma,
                 const float* __restrict__ bn_beta,
                 short* __restrict__ WHh, short* __restrict__ W0h, float* __restrict__ bf0)
{
    __shared__ float scs[NG], shs[NG];
    int tid = threadIdx.x;
    if (tid < NG){
        float N = (tid < 2) ? 4096.f * NPAIR * NWIN : 4096.f * NF * NWIN;
        float m = accum[tid] / N;
        float v = accum[NG + tid] / N - m * m;
        float cw = conv_w[0];
        float A = bn_gamma[tid] * rsqrtf(cw * cw * v + 1e-5f);
        scs[tid] = A * cw;
        shs[tid] = bn_beta[tid] - A * cw * m;
    }
    __syncthreads();
    const int NH = 3 * 2 * 12 * 64 * 8;    // 36864
    const int N0 = 7 * 12 * 64 * 8;        // 43008
    for (int i = blockIdx.x * 256 + tid; i < NH + N0; i += gridDim.x * 256){
        if (i < NH){
            int j = i & 7, lane = (i >> 3) & 63, rest = i >> 9;
            int ct = rest % 12; rest /= 12;
            int ks = rest & 1, m = rest >> 1;
            int gg = ct * 16 + (lane & 15);
            int k = ks * 32 + ((lane >> 4) << 3) + j;
            const float* Wm = (m == 0) ? Whh0 : (m == 1) ? Wih1 : Whh1;
            WHh[i] = bf16rne(Wm[gg * HID + k]);
        } else {
            int e2 = i - NH;
            int j = e2 & 7, lane = (e2 >> 3) & 63, rest = e2 >> 9;
            int ct = rest % 12, ks = rest / 12;
            int gg = ct * 16 + (lane & 15);
            int k = ks * 32 + ((lane >> 4) << 3) + j;
            float v = (k < DIN) ? Wih0[gg * DIN + k] * scs[grp_of(k)] : 0.f;
            W0h[e2] = bf16rne(v);
        }
    }
    if (blockIdx.x == 0 && tid < GATES){
        float s = bih0[tid];
        for (int k = 0; k < DIN; ++k) s += Wih0[tid * DIN + k] * shs[grp_of(k)];
        bf0[tid] = s;
    }
}

// ---------------------------------------------------------------------------
// rec: unchanged (waves 0-3 MFMA w/ VGPR-resident weights; waves 4-7 helpers).
// ---------------------------------------------------------------------------
__device__ __forceinline__ void stage_fa(short (*fab)[64][8], int tix,
                                         const float* __restrict__ feat32, int ht)
{
    for (int q = ht; q < 448; q += 256){
        int c = q >> 4, e = q & 15;
        float vv[8];
        const float* src = &feat32[((size_t)tix * 16 + e) * FROW + c * 8];
        if (c < 26){
            float4 u0 = *(const float4*)src, u1 = *(const float4*)(src + 4);
            vv[0]=u0.x; vv[1]=u0.y; vv[2]=u0.z; vv[3]=u0.w;
            vv[4]=u1.x; vv[5]=u1.y; vv[6]=u1.z; vv[7]=u1.w;
        } else if (c == 26){
            float4 u0 = *(const float4*)src;
            vv[0]=u0.x; vv[1]=u0.y; vv[2]=u0.z; vv[3]=u0.w;
            vv[4]=0.f; vv[5]=0.f; vv[6]=0.f; vv[7]=0.f;
        } else {
            #pragma unroll
            for (int j = 0; j < 8; ++j) vv[j] = 0.f;
        }
        bf16x8 h8, l8;
        #pragma unroll
        for (int j = 0; j < 8; ++j){ short hi, lo; split2(vv[j], hi, lo); h8[j] = hi; l8[j] = lo; }
        *(bf16x8*)&fab[(c >> 2) * 2 + 0][e + 16 * (c & 3)][0] = h8;
        *(bf16x8*)&fab[(c >> 2) * 2 + 1][e + 16 * (c & 3)][0] = l8;
    }
}

__global__ __launch_bounds__(512, 2)
void rec_kernel(const float* __restrict__ feat32,
                const short* __restrict__ WHh, const short* __restrict__ W0h,
                const float* __restrict__ bf0, const float* __restrict__ bhh0,
                const float* __restrict__ bih1, const float* __restrict__ bhh1,
                float* __restrict__ out)
{
    __shared__ __align__(16) short fa[2][14][64][8];
    __shared__ __align__(16) short hp[4][16][72];
    __shared__ float aar[4][16][68];
    int tid = threadIdx.x;
    int w = tid >> 6, l = tid & 63;
    int blk = blockIdx.x;

    for (int i = tid; i < 4 * 16 * 72; i += 512) ((short*)hp)[i] = 0;

    if (w < 4){
        int lm = l & 15, kb = l >> 4;
        int jc = w * 16 + lm;
        bf16x8 WH_[3][2][3];
        #pragma unroll
        for (int m = 0; m < 3; ++m)
            #pragma unroll
            for (int ks = 0; ks < 2; ++ks)
                #pragma unroll
                for (int ro = 0; ro < 3; ++ro)
                    WH_[m][ks][ro] = *(const bf16x8*)&WHh[((((m * 2 + ks) * 12) + (ro * 4 + w)) * 64 + l) * 8];
        bf16x8 W0_[7][3];
        #pragma unroll
        for (int ks = 0; ks < 7; ++ks)
            #pragma unroll
            for (int ro = 0; ro < 3; ++ro)
                W0_[ks][ro] = *(const bf16x8*)&W0h[(((ks * 12) + (ro * 4 + w)) * 64 + l) * 8];

        float cr0 = bf0[jc]       + bhh0[jc];
        float cz0 = bf0[jc + 64]  + bhh0[jc + 64];
        float cin0 = bf0[jc + 128];
        float chn0 = bhh0[jc + 128];
        float cr1 = bih1[jc]      + bhh1[jc];
        float cz1 = bih1[jc + 64] + bhh1[jc + 64];
        float cin1 = bih1[jc + 128];
        float chn1 = bhh1[jc + 128];

        __syncthreads();   // P0
        #pragma unroll 1
        for (int t = 0; t < NWIN; ++t){
            int buf = t & 1;
            bf16x8 h0h[2], h0l[2], h1h[2], h1l[2];
            #pragma unroll
            for (int ks = 0; ks < 2; ++ks){
                int off = ks * 32 + kb * 8;
                h0h[ks] = *(const bf16x8*)&hp[0][lm][off];
                h0l[ks] = *(const bf16x8*)&hp[1][lm][off];
                h1h[ks] = *(const bf16x8*)&hp[2][lm][off];
                h1l[ks] = *(const bf16x8*)&hp[3][lm][off];
            }
            f32x4 ar0 = {cr0, cr0, cr0, cr0};
            f32x4 az0 = {cz0, cz0, cz0, cz0};
            f32x4 ain0 = {cin0, cin0, cin0, cin0};
            f32x4 ahn0 = {chn0, chn0, chn0, chn0};
            f32x4 ar1 = {cr1, cr1, cr1, cr1};
            f32x4 az1 = {cz1, cz1, cz1, cz1};
            f32x4 ahn1 = {chn1, chn1, chn1, chn1};
            #pragma unroll
            for (int ks = 0; ks < 2; ++ks){
                ar0 = MFMA(h0h[ks], WH_[0][ks][0], ar0);  ar0 = MFMA(h0l[ks], WH_[0][ks][0], ar0);
                az0 = MFMA(h0h[ks], WH_[0][ks][1], az0);  az0 = MFMA(h0l[ks], WH_[0][ks][1], az0);
                ahn0 = MFMA(h0h[ks], WH_[0][ks][2], ahn0); ahn0 = MFMA(h0l[ks], WH_[0][ks][2], ahn0);
                ar1 = MFMA(h1h[ks], WH_[2][ks][0], ar1);  ar1 = MFMA(h1l[ks], WH_[2][ks][0], ar1);
                az1 = MFMA(h1h[ks], WH_[2][ks][1], az1);  az1 = MFMA(h1l[ks], WH_[2][ks][1], az1);
                ahn1 = MFMA(h1h[ks], WH_[2][ks][2], ahn1); ahn1 = MFMA(h1l[ks], WH_[2][ks][2], ahn1);
            }
            #pragma unroll
            for (int ks = 0; ks < 7; ++ks){
                bf16x8 Fh = *(const bf16x8*)&fa[buf][ks * 2 + 0][l][0];
                bf16x8 Fl = *(const bf16x8*)&fa[buf][ks * 2 + 1][l][0];
                ar0 = MFMA(Fh, W0_[ks][0], ar0);  ar0 = MFMA(Fl, W0_[ks][0], ar0);
                az0 = MFMA(Fh, W0_[ks][1], az0);  az0 = MFMA(Fl, W0_[ks][1], az0);
                ain0 = MFMA(Fh, W0_[ks][2], ain0); ain0 = MFMA(Fl, W0_[ks][2], ain0);
            }
            #pragma unroll
            for (int i = 0; i < 4; ++i){
                int row = kb * 4 + i;
                aar[0][row][jc] = ar0[i];
                aar[1][row][jc] = az0[i];
                aar[2][row][jc] = ain0[i];
                aar[3][row][jc] = ahn0[i];
            }
            __syncthreads();   // B1
            __syncthreads();   // B2
            bf16x8 n0h[2], n0l[2];
            #pragma unroll
            for (int ks = 0; ks < 2; ++ks){
                int off = ks * 32 + kb * 8;
                n0h[ks] = *(const bf16x8*)&hp[0][lm][off];
                n0l[ks] = *(const bf16x8*)&hp[1][lm][off];
            }
            f32x4 ain1 = {cin1, cin1, cin1, cin1};
            #pragma unroll
            for (int ks = 0; ks < 2; ++ks){
                ar1 = MFMA(n0h[ks], WH_[1][ks][0], ar1);  ar1 = MFMA(n0l[ks], WH_[1][ks][0], ar1);
                az1 = MFMA(n0h[ks], WH_[1][ks][1], az1);  az1 = MFMA(n0l[ks], WH_[1][ks][1], az1);
                ain1 = MFMA(n0h[ks], WH_[1][ks][2], ain1); ain1 = MFMA(n0l[ks], WH_[1][ks][2], ain1);
            }
            #pragma unroll
            for (int i = 0; i < 4; ++i){
                int row = kb * 4 + i;
                aar[0][row][jc] = ar1[i];
                aar[1][row][jc] = az1[i];
                aar[2][row][jc] = ain1[i];
                aar[3][row][jc] = ahn1[i];
            }
            __syncthreads();   // B3
            __syncthreads();   // B4
        }
    } else {
        int ht = tid - 256;
        int j = ht & 63, rr = ht >> 6;
        float h0r[4] = {0.f, 0.f, 0.f, 0.f};
        float h1r[4] = {0.f, 0.f, 0.f, 0.f};
        stage_fa(fa[0], blk * NWIN + 0, feat32, ht);
        __syncthreads();   // P0
        #pragma unroll 1
        for (int t = 0; t < NWIN; ++t){
            int buf = t & 1;
            if (t < NWIN - 1) stage_fa(fa[buf ^ 1], blk * NWIN + t + 1, feat32, ht);
            __syncthreads();   // B1
            #pragma unroll
            for (int i = 0; i < 4; ++i){
                int row = rr + i * 4;
                float a  = aar[0][row][j], z_ = aar[1][row][j];
                float in_ = aar[2][row][j], hn = aar[3][row][j];
                float rg = sigm(a), zg = sigm(z_);
                float nn = tanhfast(in_ + rg * hn);
                float h = (1.f - zg) * nn + zg * h0r[i];
                h0r[i] = h;
                short hi, lo; split2(h, hi, lo);
                hp[0][row][j] = hi;
                hp[1][row][j] = lo;
            }
            __syncthreads();   // B2
            __syncthreads();   // B3
            #pragma unroll
            for (int i = 0; i < 4; ++i){
                int row = rr + i * 4;
                float a  = aar[0][row][j], z_ = aar[1][row][j];
                float in_ = aar[2][row][j], hn = aar[3][row][j];
                float rg = sigm(a), zg = sigm(z_);
                float nn = tanhfast(in_ + rg * hn);
                float h = (1.f - zg) * nn + zg * h1r[i];
                h1r[i] = h;
                short hi, lo; split2(h, hi, lo);
                hp[2][row][j] = hi;
                hp[3][row][j] = lo;
            }
            __syncthreads();   // B4
        }
        #pragma unroll
        for (int i = 0; i < 4; ++i)
            out[((size_t)(blk * 16) + rr + i * 4) * HID + j] = h1r[i];
    }
}

// ---------------------------------------------------------------------------
extern "C" void kernel_launch(void* const* d_in, const int* in_sizes, int n_in,
                              void* d_out, int out_size, void* d_ws, size_t ws_size,
                              hipStream_t stream) {
    const float* data     = (const float*)d_in[0];
    const float* conv_w   = (const float*)d_in[1];
    const float* bn_gamma = (const float*)d_in[3];
    const float* bn_beta  = (const float*)d_in[4];
    const float* Wih0     = (const float*)d_in[5];
    const float* Whh0     = (const float*)d_in[6];
    const float* bih0     = (const float*)d_in[7];
    const float* bhh0     = (const float*)d_in[8];
    const float* Wih1     = (const float*)d_in[9];
    const float* Whh1     = (const float*)d_in[10];
    const float* bih1     = (const float*)d_in[11];
    const float* bhh1     = (const float*)d_in[12];
    float* out = (float*)d_out;

    char* ws = (char*)d_ws;
    const size_t feat32_bytes = (size_t)NGRP * NWIN * 16 * FROW * 4;   // 83,361,792
    const size_t WH_BYTES = 3 * 2 * 12 * 64 * 8 * 2;                    // 73,728
    const size_t W0_BYTES = 7 * 12 * 64 * 8 * 2;                        // 86,016
    const size_t P1_BYTES = (size_t)24 * NW1 * 4;                       // 1,474,560

    float* feat32 = (float*)ws;
    short* WHh  = (short*)(ws + feat32_bytes);
    short* W0h  = (short*)(ws + feat32_bytes + WH_BYTES);
    float* bf0  = (float*)(ws + feat32_bytes + WH_BYTES + W0_BYTES);
    float* accum = (float*)(ws + feat32_bytes + WH_BYTES + W0_BYTES + 1024);
    float* part1 = (float*)(ws + feat32_bytes + WH_BYTES + W0_BYTES + 2048);
    float* part2 = (float*)(ws + feat32_bytes + WH_BYTES + W0_BYTES + 2048 + P1_BYTES);

    s1_kernel<<<3840, 256, 0, stream>>>(data, feat32, part1);
    s2_kernel<<<4096, 256, 0, stream>>>(data, feat32, part2);
    reduce_kernel<<<28, 256, 0, stream>>>(part1, part2, accum);
    prep_kernel<<<64, 256, 0, stream>>>(Wih0, Whh0, Wih1, Whh1, bih0, accum,
                                        conv_w, bn_gamma, bn_beta, WHh, W0h, bf0);
    rec_kernel<<<NGRP, 512, 0, stream>>>(feat32, WHh, W0h, bf0,
                                         bhh0, bih1, bhh1, out);
}